// Round 6
// baseline (218.327 us; speedup 1.0000x reference)
//
#include <hip/hip_runtime.h>
#include <hip/hip_bf16.h>

// GDGCN: out[b,c,m,t] = sum_n softmax_row(relu(t1 nv2^T))[n,m] * x[b,c,n,t]
// t1 = nv1 @ (sum_d tv[d] k[d,:,:]);  N=8192, D=32, cols = B*C*T = 192.
// R17: R=2 barrier-free k_mega. Calibrated model: VALU-busy ~= R x 14.5us
// (R15: R=4 -> 57us; R16: R=1 -> 18us, both match). R16's R=1 lost to
// LATENCY (VALUBusy 17 / MfmaUtil 11 / Occ 20: y loads consumed same-iter,
// 2 waves/SIMD, no prefetch). R17 keeps R15's PROVEN one-slice-ahead
// prefetch pipeline and splits the 4 waves 2x2 over (m, cols): wave
// (wm,wc) owns 32 m x 96 cols. Gen R=4->2, per-slice loads 6y+2t1,
// consumed one iter after issue. acc 48 + y 48 + t1 16 + bg/e/d ~40
// => ~156 VGPR -> __launch_bounds__(256,3) = 3 waves/SIMD.
// Gen identity (HW-verified R13/R15): gen A-frag loads t1 rows permuted
// n_g(row)=8*(row>>2)+(row&3), +4 for phase B; gen 16x16x32 output concat
// {A.r0..3,B.r0..3} IS the bf16x8 B-frag of the acc 16x16x32 MFMA.
// E-pack: bit-exact RNE (pk_rne) -- v_cvt_pk_bf16_f32 is NOT RNE on
// gfx950 (R14 fail). No LDS, no __syncthreads in k_mega.

#define NN 8192
#define DD 32
#define TT 12
#define NSPLIT 8
#define CHUNK 1024

typedef __attribute__((ext_vector_type(8))) short bf16x8;
typedef __attribute__((ext_vector_type(4))) float f32x4;
typedef __attribute__((ext_vector_type(4))) unsigned int u32x4;

static __device__ __forceinline__ unsigned short f2bf(float f) {
  unsigned int u = __float_as_uint(f);
  u = (u + 0x7FFFu + ((u >> 16) & 1u)) >> 16;  // RNE bf16
  return (unsigned short)u;
}

static __device__ __forceinline__ float fexp2(float x) {
#if __has_builtin(__builtin_amdgcn_exp2f)
  return __builtin_amdgcn_exp2f(x);
#else
  return __builtin_exp2f(x);
#endif
}

#define MFMA32(A, B, C) __builtin_amdgcn_mfma_f32_16x16x32_bf16((A), (B), (C), 0, 0, 0)

// pack two f32 -> one u32 of 2x bf16, RNE, bit-identical to f2bf pairs
static __device__ __forceinline__ unsigned int pk_rne(float a, float b) {
  unsigned int ua = __float_as_uint(a);
  unsigned int ub = __float_as_uint(b);
  ua = ua + 0x7FFFu + ((ua >> 16) & 1u);
  ub = ub + 0x7FFFu + ((ub >> 16) & 1u);
  return (ua >> 16) | (ub & 0xFFFF0000u);  // v_lshrrev + v_and_or_b32
}

// relu -> exp2 -> RNE pack 8 f32 to bf16x8 (element e = k-slot q*8+e)
static __device__ __forceinline__ bf16x8 relu_exp2_pack(f32x4 lo, f32x4 hi) {
  u32x4 t;
  t[0] = pk_rne(fexp2(fmaxf(lo[0], 0.f)), fexp2(fmaxf(lo[1], 0.f)));
  t[1] = pk_rne(fexp2(fmaxf(lo[2], 0.f)), fexp2(fmaxf(lo[3], 0.f)));
  t[2] = pk_rne(fexp2(fmaxf(hi[0], 0.f)), fexp2(fmaxf(hi[1], 0.f)));
  t[3] = pk_rne(fexp2(fmaxf(hi[2], 0.f)), fexp2(fmaxf(hi[3], 0.f)));
  return __builtin_bit_cast(bf16x8, t);
}

// ---- fused: core = tv.k ; t1 = (nv1@core)*log2e (bf16) ; nv2 -> bf16 ; sums=0
__global__ __launch_bounds__(256) void k_prep(const float* __restrict__ nv1,
                                              const float* __restrict__ nv2,
                                              const float* __restrict__ timevec,
                                              const float* __restrict__ kk,
                                              const int* __restrict__ tind,
                                              unsigned short* __restrict__ t1b,
                                              unsigned short* __restrict__ nv2b,
                                              float* __restrict__ sums) {
  __shared__ float cs[1024];
  const int tid = threadIdx.x;
  if (tid < 128) sums[blockIdx.x * 128 + tid] = 0.f;
  const float* tv = timevec + (size_t)tind[0] * DD;
  for (int idx = tid; idx < 1024; idx += 256) {
    float acc = 0.f;
#pragma unroll
    for (int d = 0; d < DD; ++d) acc += tv[d] * kk[d * 1024 + idx];
    cs[idx] = acc;
  }
  __syncthreads();
  const int nbase = blockIdx.x * 128;
  const int f = tid & 31, sub = tid >> 5;
#pragma unroll 4
  for (int it = 0; it < 16; ++it) {
    const int n = nbase + it * 8 + sub;
    const float* nr = nv1 + (size_t)n * DD;
    float acc = 0.f;
#pragma unroll
    for (int e = 0; e < DD; ++e) acc += nr[e] * cs[e * DD + f];
    t1b[(size_t)n * DD + f] = f2bf(acc * 1.4426950408889634f);  // fold log2(e)
  }
#pragma unroll 4
  for (int it = 0; it < 16; ++it) {
    const int idx = nbase * DD + it * 256 + tid;
    nv2b[idx] = f2bf(nv2[idx]);
  }
}

// ---- sums[n] += sum_m exp2(relu(t1[n].nv2[m]))  grid (128 n, 8 m-chunks) ----
__global__ __launch_bounds__(256) void k_stats(const unsigned short* __restrict__ t1b,
                                               const unsigned short* __restrict__ nv2b,
                                               float* __restrict__ sums) {
  const int tid = threadIdx.x;
  const int w = tid >> 6, lane = tid & 63, q = lane >> 4, i16 = lane & 15;
  const int nbase = blockIdx.x * 64 + w * 16;
  bf16x8 a = *(const bf16x8*)(t1b + (size_t)(nbase + i16) * DD + q * 8);
  const f32x4 z4 = {0.f, 0.f, 0.f, 0.f};
  float s[4] = {0.f, 0.f, 0.f, 0.f};
  const int m0 = blockIdx.y * 1024;
  for (int mt = m0; mt < m0 + 1024; mt += 64) {
#pragma unroll
    for (int u = 0; u < 4; ++u) {
      bf16x8 b = *(const bf16x8*)(nv2b + (size_t)(mt + u * 16 + i16) * DD + q * 8);
      f32x4 d = __builtin_amdgcn_mfma_f32_16x16x32_bf16(a, b, z4, 0, 0, 0);
#pragma unroll
      for (int r = 0; r < 4; ++r) s[r] += fexp2(fmaxf(d[r], 0.f));
    }
  }
#pragma unroll
  for (int r = 0; r < 4; ++r)
    for (int off = 1; off < 16; off <<= 1) s[r] += __shfl_xor(s[r], off, 64);
  if (i16 == 0) {
#pragma unroll
    for (int r = 0; r < 4; ++r) atomicAdd(&sums[nbase + q * 4 + r], s[r]);
  }
}

// ---- yT[col][n] = bf16(x[bc][n][t] / sums[n]) via LDS transpose (pad 12->13) ----
__global__ __launch_bounds__(256) void k_y(const float* __restrict__ x,
                                           const float* __restrict__ sums,
                                           unsigned short* __restrict__ yT) {
  __shared__ float xs[3328];  // 256 * 13
  const int tid = threadIdx.x;
  const int n0 = blockIdx.x * 256;
  const int bc = blockIdx.y;
  const float* xp = x + (size_t)bc * NN * TT + (size_t)n0 * TT;
#pragma unroll
  for (int j = 0; j < 12; ++j) {
    const int idx = j * 256 + tid;
    xs[(idx / 12) * 13 + idx % 12] = xp[idx];
  }
  __syncthreads();
  const float rinv = 1.0f / sums[n0 + tid];
#pragma unroll
  for (int t = 0; t < 12; ++t)
    yT[(size_t)(bc * TT + t) * NN + n0 + tid] = f2bf(xs[tid * 13 + t] * rinv);
}

// ---- k_mega: part[nc][col][m] = sum_{n in chunk} E[n][m] * y[col][n] ----
// grid (128 m-blocks of 64, 8 chunks of 1024 n); 256 thr = 4 waves.
// Wave (wm = w>>1, wc = w&1): m-strips [mb+wm*32, +32), cols
// [wc*96, +96). Per 32-n slice: 4 gen MFMAs -> relu/exp2/RNE-pack ->
// 12 acc MFMAs; y/t1 prefetched one slice ahead (R15-proven pipeline).
__global__ __launch_bounds__(256, 3) void k_mega(const unsigned short* __restrict__ t1b,
                                                 const unsigned short* __restrict__ nv2b,
                                                 const unsigned short* __restrict__ yT,
                                                 float* __restrict__ part) {
  const int tid = threadIdx.x;
  const int w = tid >> 6, lane = tid & 63, q = lane >> 4, i16 = lane & 15;
  const int wm = w >> 1, wc = w & 1;
  const int mw = blockIdx.x * 64 + wm * 32;  // wave's m-base
  const int cw = wc * 96;                    // wave's col-base
  const int nt0 = blockIdx.y * CHUNK;

  // gen B-frags (loop-invariant): bg[ms][k=d] at col m = mw+ms*16+i16
  bf16x8 bg[2];
#pragma unroll
  for (int ms = 0; ms < 2; ++ms)
    bg[ms] = *(const bf16x8*)(nv2b + (size_t)(mw + ms * 16 + i16) * DD + q * 8);

  f32x4 acc[6][2];
#pragma unroll
  for (int c = 0; c < 6; ++c)
#pragma unroll
    for (int ms = 0; ms < 2; ++ms) acc[c][ms] = (f32x4){0.f, 0.f, 0.f, 0.f};

  // gen A-frag row permutation (HW-verified R13): A-row i16 <- t1 row
  // nt + 8*(i16>>2)+(i16&3), +4 for phase B.
  const int perm = ((i16 >> 2) << 3) | (i16 & 3);
  const unsigned short* tp = t1b + (size_t)(nt0 + perm) * DD + q * 8;
  // y A-frags: y[col = cw + c*16 + i16][n = nt + q*8 + e]
  const unsigned short* yp = yT + (size_t)(cw + i16) * NN + nt0 + q * 8;

  const f32x4 z4 = {0.f, 0.f, 0.f, 0.f};

  // ---- prologue: e = E[0], y = y[0], alo/ahi = t1[1] ----
  bf16x8 alo = *(const bf16x8*)tp;
  bf16x8 ahi = *(const bf16x8*)(tp + 4 * DD);
  bf16x8 e0, e1;
  {
    f32x4 d00 = MFMA32(alo, bg[0], z4);
    f32x4 d01 = MFMA32(ahi, bg[0], z4);
    f32x4 d10 = MFMA32(alo, bg[1], z4);
    f32x4 d11 = MFMA32(ahi, bg[1], z4);
    e0 = relu_exp2_pack(d00, d01);
    e1 = relu_exp2_pack(d10, d11);
  }
  bf16x8 y[6];
#pragma unroll
  for (int c = 0; c < 6; ++c) y[c] = *(const bf16x8*)(yp + (size_t)(c * 16) * NN);
  alo = *(const bf16x8*)(tp + 32 * DD);
  ahi = *(const bf16x8*)(tp + 36 * DD);

  for (int sl = 1; sl < 32; ++sl) {
    // loads: y[sl] and t1[sl+1]. t1 prefetch at sl=31 reads one tile past
    // the chunk (chunk 7: lands in nv2b region of workspace; never used).
    const int o = sl * 32;
    bf16x8 yn[6];
#pragma unroll
    for (int c = 0; c < 6; ++c)
      yn[c] = *(const bf16x8*)(yp + (size_t)(c * 16) * NN + o);
    bf16x8 alo_n = *(const bf16x8*)(tp + (size_t)(o + 32) * DD);
    bf16x8 ahi_n = *(const bf16x8*)(tp + (size_t)(o + 36) * DD);

    // gen slice sl logits (4 MFMAs, independent of acc below)
    f32x4 d00 = MFMA32(alo, bg[0], z4);
    f32x4 d01 = MFMA32(ahi, bg[0], z4);
    f32x4 d10 = MFMA32(alo, bg[1], z4);
    f32x4 d11 = MFMA32(ahi, bg[1], z4);

    // acc slice sl-1 (12 MFMAs) using y (= y[sl-1]) and e0/e1
#pragma unroll
    for (int c = 0; c < 6; ++c) acc[c][0] = MFMA32(y[c], e0, acc[c][0]);
    e0 = relu_exp2_pack(d00, d01);  // pack overlaps acc MFMAs
#pragma unroll
    for (int c = 0; c < 6; ++c) acc[c][1] = MFMA32(y[c], e1, acc[c][1]);
    e1 = relu_exp2_pack(d10, d11);

#pragma unroll
    for (int c = 0; c < 6; ++c) y[c] = yn[c];
    alo = alo_n; ahi = ahi_n;
  }

  // ---- epilogue: acc slice 31 ----
#pragma unroll
  for (int c = 0; c < 6; ++c) {
    acc[c][0] = MFMA32(y[c], e0, acc[c][0]);
    acc[c][1] = MFMA32(y[c], e1, acc[c][1]);
  }

  // epilogue: lane holds col = cw + c*16 + q*4 + r, m = mw + ms*16 + i16
  float* pp = part + (size_t)blockIdx.y * 192 * NN;
#pragma unroll
  for (int c = 0; c < 6; ++c)
#pragma unroll
    for (int ms = 0; ms < 2; ++ms) {
      const int colbase = cw + c * 16 + q * 4;
      const int m = mw + ms * 16 + i16;
#pragma unroll
      for (int r = 0; r < 4; ++r)
        pp[(size_t)(colbase + r) * NN + m] = acc[c][ms][r];
    }
}

// ---- reduce NSPLIT partials + transpose to out[bc][m][t] (pad 12->13) ----
__global__ __launch_bounds__(256) void k_reduce(const float* __restrict__ part,
                                                float* __restrict__ out) {
  __shared__ float os[3328];  // 256 * 13
  const int tid = threadIdx.x;
  const int m0 = blockIdx.x * 256;
  const int bc = blockIdx.y;
#pragma unroll
  for (int t = 0; t < 12; ++t) {
    const int col = bc * TT + t;
    float s = 0.f;
#pragma unroll
    for (int nc = 0; nc < NSPLIT; ++nc)
      s += part[((size_t)nc * 192 + col) * NN + m0 + tid];
    os[tid * 13 + t] = s;
  }
  __syncthreads();
  float* op = out + (size_t)bc * NN * TT + (size_t)m0 * TT;
#pragma unroll
  for (int j = 0; j < 12; ++j) {
    const int idx = j * 256 + tid;
    op[idx] = os[(idx / 12) * 13 + idx % 12];
  }
}

extern "C" void kernel_launch(void* const* d_in, const int* in_sizes, int n_in,
                              void* d_out, int out_size, void* d_ws, size_t ws_size,
                              hipStream_t stream) {
  const float* x = (const float*)d_in[0];
  const float* nv1 = (const float*)d_in[1];
  const float* nv2 = (const float*)d_in[2];
  const float* tv = (const float*)d_in[3];
  const float* kk = (const float*)d_in[4];
  const int* tind = (const int*)d_in[5];
  float* out = (float*)d_out;

  char* ws = (char*)d_ws;
  unsigned short* t1b  = (unsigned short*)(ws);            //  524288 B
  unsigned short* nv2b = (unsigned short*)(ws + 524288);   //  524288 B
  float* sums          = (float*)(ws + 1048576);           //   32768 B
  unsigned short* yT   = (unsigned short*)(ws + 1081344);  // 3145728 B -> 4227072
  float* part          = (float*)(ws + 4227072);           // 50331648 B -> 54558720

  k_prep<<<64, 256, 0, stream>>>(nv1, nv2, tv, kk, tind, t1b, nv2b, sums);
  k_stats<<<dim3(128, 8), 256, 0, stream>>>(t1b, nv2b, sums);
  k_y<<<dim3(32, 16), 256, 0, stream>>>(x, sums, yT);
  k_mega<<<dim3(128, NSPLIT), 256, 0, stream>>>(t1b, nv2b, yT, part);
  k_reduce<<<dim3(32, 16), 256, 0, stream>>>(part, out);
}

// Round 7
// 177.713 us; speedup vs baseline: 1.2285x; 1.2285x over previous
//
#include <hip/hip_runtime.h>
#include <hip/hip_bf16.h>

// GDGCN: out[b,c,m,t] = sum_n softmax_row(relu(t1 nv2^T))[n,m] * x[b,c,n,t]
// t1 = nv1 @ (sum_d tv[d] k[d,:,:]);  N=8192, D=32, cols = B*C*T = 192.
// R18: back to the measured-best structure (R11 k_mega, 71.6us) with ONE
// change: per-stage __syncthreads() (which drains vmcnt(0), stalling on
// the in-flight y/t1 global loads at every one of 16 stages) is replaced
// by raw s_barrier + lgkmcnt(0)-only (LDS dbuf needs only lgkmcnt; the
// compiler still inserts vmcnt waits before each load's consumer). The
// barrier-free m-split redesigns (R15/16/17) all lost: col-split + LDS-E
// has strictly less data movement (y fills disjoint, E shared at R=1);
// their regen either cost R x 14.5us VALU (R15) or uncovered L1-scatter
// latency (R16/17). k_stats gains a 1-iter b-prefetch (bit-identical
// ops). k_y/k_reduce keep the proven 12->13 LDS pad.

#define NN 8192
#define DD 32
#define TT 12
#define NSPLIT 8
#define CHUNK 1024
#define ESTR 72  // LDS row stride (ushort); R6-proven layout

typedef __attribute__((ext_vector_type(8))) short bf16x8;
typedef __attribute__((ext_vector_type(4))) short bf16x4;
typedef __attribute__((ext_vector_type(4))) float f32x4;

static __device__ __forceinline__ unsigned short f2bf(float f) {
  unsigned int u = __float_as_uint(f);
  u = (u + 0x7FFFu + ((u >> 16) & 1u)) >> 16;  // RNE bf16
  return (unsigned short)u;
}

static __device__ __forceinline__ float fexp2(float x) {
#if __has_builtin(__builtin_amdgcn_exp2f)
  return __builtin_amdgcn_exp2f(x);
#else
  return __builtin_exp2f(x);
#endif
}

// Raw barrier: LDS-visibility only. Deliberately does NOT drain vmcnt, so
// global y/t1 loads stay in flight across stages (the compiler inserts
// its own vmcnt waits before consumers). sched_barrier(0) pins the
// lgkmcnt against reordering (guide rule #18).
#define RAWBAR()                                          \
  do {                                                    \
    asm volatile("s_waitcnt lgkmcnt(0)" ::: "memory");    \
    __builtin_amdgcn_sched_barrier(0);                    \
    __builtin_amdgcn_s_barrier();                         \
  } while (0)

// ---- fused: core = tv.k ; t1 = (nv1@core)*log2e (bf16) ; nv2 -> bf16 ; sums=0
__global__ __launch_bounds__(256) void k_prep(const float* __restrict__ nv1,
                                              const float* __restrict__ nv2,
                                              const float* __restrict__ timevec,
                                              const float* __restrict__ kk,
                                              const int* __restrict__ tind,
                                              unsigned short* __restrict__ t1b,
                                              unsigned short* __restrict__ nv2b,
                                              float* __restrict__ sums) {
  __shared__ float cs[1024];
  const int tid = threadIdx.x;
  if (tid < 128) sums[blockIdx.x * 128 + tid] = 0.f;
  const float* tv = timevec + (size_t)tind[0] * DD;
  for (int idx = tid; idx < 1024; idx += 256) {
    float acc = 0.f;
#pragma unroll
    for (int d = 0; d < DD; ++d) acc += tv[d] * kk[d * 1024 + idx];
    cs[idx] = acc;
  }
  __syncthreads();
  const int nbase = blockIdx.x * 128;
  const int f = tid & 31, sub = tid >> 5;
#pragma unroll 4
  for (int it = 0; it < 16; ++it) {
    const int n = nbase + it * 8 + sub;
    const float* nr = nv1 + (size_t)n * DD;
    float acc = 0.f;
#pragma unroll
    for (int e = 0; e < DD; ++e) acc += nr[e] * cs[e * DD + f];
    t1b[(size_t)n * DD + f] = f2bf(acc * 1.4426950408889634f);  // fold log2(e)
  }
#pragma unroll 4
  for (int it = 0; it < 16; ++it) {
    const int idx = nbase * DD + it * 256 + tid;
    nv2b[idx] = f2bf(nv2[idx]);
  }
}

// ---- sums[n] += sum_m exp2(relu(t1[n].nv2[m]))  grid (128 n, 8 m-chunks) ----
// 1-iter b-prefetch: loads of tile mt+64 issued before computing tile mt.
__global__ __launch_bounds__(256) void k_stats(const unsigned short* __restrict__ t1b,
                                               const unsigned short* __restrict__ nv2b,
                                               float* __restrict__ sums) {
  const int tid = threadIdx.x;
  const int w = tid >> 6, lane = tid & 63, q = lane >> 4, i16 = lane & 15;
  const int nbase = blockIdx.x * 64 + w * 16;
  bf16x8 a = *(const bf16x8*)(t1b + (size_t)(nbase + i16) * DD + q * 8);
  const f32x4 z4 = {0.f, 0.f, 0.f, 0.f};
  float s[4] = {0.f, 0.f, 0.f, 0.f};
  const int m0 = blockIdx.y * 1024;
#define LDB(mt, u) (*(const bf16x8*)(nv2b + (size_t)((mt) + (u)*16 + i16) * DD + q * 8))
  bf16x8 b0 = LDB(m0, 0), b1 = LDB(m0, 1), b2 = LDB(m0, 2), b3 = LDB(m0, 3);
  for (int mt = m0; mt < m0 + 1024; mt += 64) {
    const int mtn = (mt + 64 < m0 + 1024) ? (mt + 64) : mt;  // clamp: dummy reload
    bf16x8 n0 = LDB(mtn, 0), n1 = LDB(mtn, 1), n2 = LDB(mtn, 2), n3 = LDB(mtn, 3);
    f32x4 d;
    d = __builtin_amdgcn_mfma_f32_16x16x32_bf16(a, b0, z4, 0, 0, 0);
#pragma unroll
    for (int r = 0; r < 4; ++r) s[r] += fexp2(fmaxf(d[r], 0.f));
    d = __builtin_amdgcn_mfma_f32_16x16x32_bf16(a, b1, z4, 0, 0, 0);
#pragma unroll
    for (int r = 0; r < 4; ++r) s[r] += fexp2(fmaxf(d[r], 0.f));
    d = __builtin_amdgcn_mfma_f32_16x16x32_bf16(a, b2, z4, 0, 0, 0);
#pragma unroll
    for (int r = 0; r < 4; ++r) s[r] += fexp2(fmaxf(d[r], 0.f));
    d = __builtin_amdgcn_mfma_f32_16x16x32_bf16(a, b3, z4, 0, 0, 0);
#pragma unroll
    for (int r = 0; r < 4; ++r) s[r] += fexp2(fmaxf(d[r], 0.f));
    b0 = n0; b1 = n1; b2 = n2; b3 = n3;
  }
#undef LDB
#pragma unroll
  for (int r = 0; r < 4; ++r)
    for (int off = 1; off < 16; off <<= 1) s[r] += __shfl_xor(s[r], off, 64);
  if (i16 == 0) {
#pragma unroll
    for (int r = 0; r < 4; ++r) atomicAdd(&sums[nbase + q * 4 + r], s[r]);
  }
}

// ---- yT[col][n] = bf16(x[bc][n][t] / sums[n]) via LDS transpose (pad 12->13) ----
__global__ __launch_bounds__(256) void k_y(const float* __restrict__ x,
                                           const float* __restrict__ sums,
                                           unsigned short* __restrict__ yT) {
  __shared__ float xs[3328];  // 256 * 13
  const int tid = threadIdx.x;
  const int n0 = blockIdx.x * 256;
  const int bc = blockIdx.y;
  const float* xp = x + (size_t)bc * NN * TT + (size_t)n0 * TT;
#pragma unroll
  for (int j = 0; j < 12; ++j) {
    const int idx = j * 256 + tid;
    xs[(idx / 12) * 13 + idx % 12] = xp[idx];
  }
  __syncthreads();
  const float rinv = 1.0f / sums[n0 + tid];
#pragma unroll
  for (int t = 0; t < 12; ++t)
    yT[(size_t)(bc * TT + t) * NN + n0 + tid] = f2bf(xs[tid * 13 + t] * rinv);
}

// ---- k_mega: part[nc][col][m] = sum_{n in chunk} E[n][m] * y[col][n] ----
// grid (128 m-blocks of 64, 8 chunks of 1024 n); 256 thr = 4 waves.
// Stage = 64 n, double-buffered Et[2][64][ESTR]. Gen: wave w -> E rows
// [w*16,w*16+16) x 64 n (4 MFMAs + 16 exp2 + 4 b64 writes). Acc: wave w ->
// coltiles [w*3,w*3+3) x 4 m-subs x 2 k-steps = 24 MFMAs. One RAW barrier
// per stage (lgkmcnt-only; global loads never drained). 4 blocks/CU.
__global__ __launch_bounds__(256, 4) void k_mega(const unsigned short* __restrict__ t1b,
                                                 const unsigned short* __restrict__ nv2b,
                                                 const unsigned short* __restrict__ yT,
                                                 float* __restrict__ part) {
  const int tid = threadIdx.x;
  const int w = tid >> 6, lane = tid & 63, q = lane >> 4, i16 = lane & 15;
  const int mb = blockIdx.x * 64;
  const int nt0 = blockIdx.y * CHUNK;

  __shared__ unsigned short Ew[2][64][ESTR];  // 18432 B

  // gen B-frag (loop-invariant): B[d][m=i16] = nv2[mb + w*16 + i16][d]
  const bf16x8 bg = *(const bf16x8*)(nv2b + (size_t)(mb + w * 16 + i16) * DD + q * 8);
  const int rowm = w * 16 + i16;

  const f32x4 z4 = {0.f, 0.f, 0.f, 0.f};
  f32x4 acc[3][4];
#pragma unroll
  for (int c = 0; c < 3; ++c)
#pragma unroll
    for (int ms = 0; ms < 4; ++ms) acc[c][ms] = (f32x4){0.f, 0.f, 0.f, 0.f};

  // ---- prologue: generate stage 0 (64 n) into buf 0 ----
#pragma unroll
  for (int s = 0; s < 4; ++s) {
    bf16x8 at = *(const bf16x8*)(t1b + (size_t)(nt0 + s * 16 + i16) * DD + q * 8);
    f32x4 d = __builtin_amdgcn_mfma_f32_16x16x32_bf16(at, bg, z4, 0, 0, 0);
    bf16x4 e;
#pragma unroll
    for (int r = 0; r < 4; ++r) e[r] = (short)f2bf(fexp2(fmaxf(d[r], 0.f)));
    *(bf16x4*)&Ew[0][rowm][s * 16 + q * 4] = e;
  }
  RAWBAR();

  int p = 0;
  for (int st = 0; st < 16; ++st, p ^= 1) {
    const int nt = nt0 + st * 64;
    const bool more = (st < 15);

    // next-stage t1 A-frags, issued at stage top for latency
    bf16x8 atn[4];
    if (more) {
#pragma unroll
      for (int s = 0; s < 4; ++s)
        atn[s] = *(const bf16x8*)(t1b + (size_t)(nt + 64 + s * 16 + i16) * DD + q * 8);
    }

    // half-0 operands (k-step 0: n 0..31 of stage)
    bf16x8 yfr[3], efr[4];
#pragma unroll
    for (int c = 0; c < 3; ++c)
      yfr[c] = *(const bf16x8*)(yT + (size_t)((w * 3 + c) * 16 + i16) * NN + nt + q * 8);
#pragma unroll
    for (int ms = 0; ms < 4; ++ms)
      efr[ms] = *(const bf16x8*)&Ew[p][ms * 16 + i16][q * 8];

    // gen first half (s0,s1) for stage st+1
    f32x4 d0, d1;
    if (more) {
      d0 = __builtin_amdgcn_mfma_f32_16x16x32_bf16(atn[0], bg, z4, 0, 0, 0);
      d1 = __builtin_amdgcn_mfma_f32_16x16x32_bf16(atn[1], bg, z4, 0, 0, 0);
    }

    // acc k-step 0 (12 MFMAs)
#pragma unroll
    for (int c = 0; c < 3; ++c)
#pragma unroll
      for (int ms = 0; ms < 4; ++ms)
        acc[c][ms] = __builtin_amdgcn_mfma_f32_16x16x32_bf16(yfr[c], efr[ms], acc[c][ms], 0, 0, 0);

    // exp2 + store s0,s1; gen + store s2,s3 (VALU overlaps MFMA pipes)
    if (more) {
      bf16x4 e0, e1;
#pragma unroll
      for (int r = 0; r < 4; ++r) {
        e0[r] = (short)f2bf(fexp2(fmaxf(d0[r], 0.f)));
        e1[r] = (short)f2bf(fexp2(fmaxf(d1[r], 0.f)));
      }
      *(bf16x4*)&Ew[p ^ 1][rowm][q * 4] = e0;
      *(bf16x4*)&Ew[p ^ 1][rowm][16 + q * 4] = e1;
      f32x4 d2 = __builtin_amdgcn_mfma_f32_16x16x32_bf16(atn[2], bg, z4, 0, 0, 0);
      f32x4 d3 = __builtin_amdgcn_mfma_f32_16x16x32_bf16(atn[3], bg, z4, 0, 0, 0);
      bf16x4 e2, e3;
#pragma unroll
      for (int r = 0; r < 4; ++r) {
        e2[r] = (short)f2bf(fexp2(fmaxf(d2[r], 0.f)));
        e3[r] = (short)f2bf(fexp2(fmaxf(d3[r], 0.f)));
      }
      *(bf16x4*)&Ew[p ^ 1][rowm][32 + q * 4] = e2;
      *(bf16x4*)&Ew[p ^ 1][rowm][48 + q * 4] = e3;
    }

    // half-1 operands + acc (k-step 1: n 32..63)
#pragma unroll
    for (int c = 0; c < 3; ++c)
      yfr[c] = *(const bf16x8*)(yT + (size_t)((w * 3 + c) * 16 + i16) * NN + nt + 32 + q * 8);
#pragma unroll
    for (int ms = 0; ms < 4; ++ms)
      efr[ms] = *(const bf16x8*)&Ew[p][ms * 16 + i16][32 + q * 8];
#pragma unroll
    for (int c = 0; c < 3; ++c)
#pragma unroll
      for (int ms = 0; ms < 4; ++ms)
        acc[c][ms] = __builtin_amdgcn_mfma_f32_16x16x32_bf16(yfr[c], efr[ms], acc[c][ms], 0, 0, 0);

    RAWBAR();  // buf p reads done; buf p^1 writes visible (lgkmcnt only)
  }

  // epilogue: lane holds col = (w*3+c)*16 + q*4 + r, m = mb + ms*16 + i16
  float* pp = part + (size_t)blockIdx.y * 192 * NN;
#pragma unroll
  for (int c = 0; c < 3; ++c)
#pragma unroll
    for (int ms = 0; ms < 4; ++ms) {
      const int colbase = (w * 3 + c) * 16 + q * 4;
      const int m = mb + ms * 16 + i16;
#pragma unroll
      for (int r = 0; r < 4; ++r)
        pp[(size_t)(colbase + r) * NN + m] = acc[c][ms][r];
    }
}

// ---- reduce NSPLIT partials + transpose to out[bc][m][t] (pad 12->13) ----
__global__ __launch_bounds__(256) void k_reduce(const float* __restrict__ part,
                                                float* __restrict__ out) {
  __shared__ float os[3328];  // 256 * 13
  const int tid = threadIdx.x;
  const int m0 = blockIdx.x * 256;
  const int bc = blockIdx.y;
#pragma unroll
  for (int t = 0; t < 12; ++t) {
    const int col = bc * TT + t;
    float s = 0.f;
#pragma unroll
    for (int nc = 0; nc < NSPLIT; ++nc)
      s += part[((size_t)nc * 192 + col) * NN + m0 + tid];
    os[tid * 13 + t] = s;
  }
  __syncthreads();
  float* op = out + (size_t)bc * NN * TT + (size_t)m0 * TT;
#pragma unroll
  for (int j = 0; j < 12; ++j) {
    const int idx = j * 256 + tid;
    op[idx] = os[(idx / 12) * 13 + idx % 12];
  }
}

extern "C" void kernel_launch(void* const* d_in, const int* in_sizes, int n_in,
                              void* d_out, int out_size, void* d_ws, size_t ws_size,
                              hipStream_t stream) {
  const float* x = (const float*)d_in[0];
  const float* nv1 = (const float*)d_in[1];
  const float* nv2 = (const float*)d_in[2];
  const float* tv = (const float*)d_in[3];
  const float* kk = (const float*)d_in[4];
  const int* tind = (const int*)d_in[5];
  float* out = (float*)d_out;

  char* ws = (char*)d_ws;
  unsigned short* t1b  = (unsigned short*)(ws);            //  524288 B
  unsigned short* nv2b = (unsigned short*)(ws + 524288);   //  524288 B
  float* sums          = (float*)(ws + 1048576);           //   32768 B
  unsigned short* yT   = (unsigned short*)(ws + 1081344);  // 3145728 B -> 4227072
  float* part          = (float*)(ws + 4227072);           // 50331648 B -> 54558720

  k_prep<<<64, 256, 0, stream>>>(nv1, nv2, tv, kk, tind, t1b, nv2b, sums);
  k_stats<<<dim3(128, 8), 256, 0, stream>>>(t1b, nv2b, sums);
  k_y<<<dim3(32, 16), 256, 0, stream>>>(x, sums, yT);
  k_mega<<<dim3(128, NSPLIT), 256, 0, stream>>>(t1b, nv2b, yT, part);
  k_reduce<<<dim3(32, 16), 256, 0, stream>>>(part, out);
}

// Round 8
// 172.978 us; speedup vs baseline: 1.2622x; 1.0274x over previous
//
#include <hip/hip_runtime.h>
#include <hip/hip_bf16.h>

// GDGCN: out[b,c,m,t] = sum_n softmax_row(relu(t1 nv2^T))[n,m] * x[b,c,n,t]
// t1 = nv1 @ (sum_d tv[d] k[d,:,:]);  N=8192, D=32, cols = B*C*T = 192.
// R19: R18 structure (proven 73us) + three additive fixes:
//  1) ESTR 72->70: efr ds_read_b128 bank pattern was 4*(i16+q) mod 32 =
//     8-way conflict (2.94x, 3.1M cyc measured). Odd dword stride 35 ->
//     (3*i16+4q) mod 32 ~ 2-way (free per m136).
//  2) all 6 y loads hoisted to stage top: half-1's latency now hides
//     under k-step-0's 12 MFMAs + pack (RAWBAR keeps them in flight;
//     R18 proved the barrier drain itself was ~free, so the win must
//     come from issue distance, not drain removal).
//  3) k_prep grid 64->128 blocks (was 25% CU utilization).
// History: R15/16/17 m-split redesigns all lost (redundant-gen VALU wall
// = R x 14.5us, or uncovered L1-scatter latency). Col-split + LDS-E at
// R=1 is data-movement-optimal. E-pack: bit-exact RNE f2bf only
// (v_cvt_pk_bf16_f32 is NOT RNE on gfx950, R14 fail).

#define NN 8192
#define DD 32
#define TT 12
#define NSPLIT 8
#define CHUNK 1024
#define ESTR 70  // LDS row stride (ushort); 35 dwords, odd -> ~2-way banks

typedef __attribute__((ext_vector_type(8))) short bf16x8;
typedef __attribute__((ext_vector_type(4))) short bf16x4;
typedef __attribute__((ext_vector_type(4))) float f32x4;

static __device__ __forceinline__ unsigned short f2bf(float f) {
  unsigned int u = __float_as_uint(f);
  u = (u + 0x7FFFu + ((u >> 16) & 1u)) >> 16;  // RNE bf16
  return (unsigned short)u;
}

static __device__ __forceinline__ float fexp2(float x) {
#if __has_builtin(__builtin_amdgcn_exp2f)
  return __builtin_amdgcn_exp2f(x);
#else
  return __builtin_exp2f(x);
#endif
}

// Raw barrier: LDS-visibility only (lgkmcnt). Global loads stay in flight
// across stages; compiler inserts vmcnt waits before consumers.
// sched_barrier(0) pins the lgkmcnt against reordering (guide rule #18).
#define RAWBAR()                                          \
  do {                                                    \
    asm volatile("s_waitcnt lgkmcnt(0)" ::: "memory");    \
    __builtin_amdgcn_sched_barrier(0);                    \
    __builtin_amdgcn_s_barrier();                         \
  } while (0)

// ---- fused: core = tv.k ; t1 = (nv1@core)*log2e (bf16) ; nv2 -> bf16 ; sums=0
// 128 blocks x 64 rows.
__global__ __launch_bounds__(256) void k_prep(const float* __restrict__ nv1,
                                              const float* __restrict__ nv2,
                                              const float* __restrict__ timevec,
                                              const float* __restrict__ kk,
                                              const int* __restrict__ tind,
                                              unsigned short* __restrict__ t1b,
                                              unsigned short* __restrict__ nv2b,
                                              float* __restrict__ sums) {
  __shared__ float cs[1024];
  const int tid = threadIdx.x;
  if (tid < 64) sums[blockIdx.x * 64 + tid] = 0.f;
  const float* tv = timevec + (size_t)tind[0] * DD;
  for (int idx = tid; idx < 1024; idx += 256) {
    float acc = 0.f;
#pragma unroll
    for (int d = 0; d < DD; ++d) acc += tv[d] * kk[d * 1024 + idx];
    cs[idx] = acc;
  }
  __syncthreads();
  const int nbase = blockIdx.x * 64;
  const int f = tid & 31, sub = tid >> 5;
#pragma unroll 4
  for (int it = 0; it < 8; ++it) {
    const int n = nbase + it * 8 + sub;
    const float* nr = nv1 + (size_t)n * DD;
    float acc = 0.f;
#pragma unroll
    for (int e = 0; e < DD; ++e) acc += nr[e] * cs[e * DD + f];
    t1b[(size_t)n * DD + f] = f2bf(acc * 1.4426950408889634f);  // fold log2(e)
  }
#pragma unroll 4
  for (int it = 0; it < 8; ++it) {
    const int idx = nbase * DD + it * 256 + tid;
    nv2b[idx] = f2bf(nv2[idx]);
  }
}

// ---- sums[n] += sum_m exp2(relu(t1[n].nv2[m]))  grid (128 n, 8 m-chunks) ----
// 1-iter b-prefetch: loads of tile mt+64 issued before computing tile mt.
__global__ __launch_bounds__(256) void k_stats(const unsigned short* __restrict__ t1b,
                                               const unsigned short* __restrict__ nv2b,
                                               float* __restrict__ sums) {
  const int tid = threadIdx.x;
  const int w = tid >> 6, lane = tid & 63, q = lane >> 4, i16 = lane & 15;
  const int nbase = blockIdx.x * 64 + w * 16;
  bf16x8 a = *(const bf16x8*)(t1b + (size_t)(nbase + i16) * DD + q * 8);
  const f32x4 z4 = {0.f, 0.f, 0.f, 0.f};
  float s[4] = {0.f, 0.f, 0.f, 0.f};
  const int m0 = blockIdx.y * 1024;
#define LDB(mt, u) (*(const bf16x8*)(nv2b + (size_t)((mt) + (u)*16 + i16) * DD + q * 8))
  bf16x8 b0 = LDB(m0, 0), b1 = LDB(m0, 1), b2 = LDB(m0, 2), b3 = LDB(m0, 3);
  for (int mt = m0; mt < m0 + 1024; mt += 64) {
    const int mtn = (mt + 64 < m0 + 1024) ? (mt + 64) : mt;  // clamp: dummy reload
    bf16x8 n0 = LDB(mtn, 0), n1 = LDB(mtn, 1), n2 = LDB(mtn, 2), n3 = LDB(mtn, 3);
    f32x4 d;
    d = __builtin_amdgcn_mfma_f32_16x16x32_bf16(a, b0, z4, 0, 0, 0);
#pragma unroll
    for (int r = 0; r < 4; ++r) s[r] += fexp2(fmaxf(d[r], 0.f));
    d = __builtin_amdgcn_mfma_f32_16x16x32_bf16(a, b1, z4, 0, 0, 0);
#pragma unroll
    for (int r = 0; r < 4; ++r) s[r] += fexp2(fmaxf(d[r], 0.f));
    d = __builtin_amdgcn_mfma_f32_16x16x32_bf16(a, b2, z4, 0, 0, 0);
#pragma unroll
    for (int r = 0; r < 4; ++r) s[r] += fexp2(fmaxf(d[r], 0.f));
    d = __builtin_amdgcn_mfma_f32_16x16x32_bf16(a, b3, z4, 0, 0, 0);
#pragma unroll
    for (int r = 0; r < 4; ++r) s[r] += fexp2(fmaxf(d[r], 0.f));
    b0 = n0; b1 = n1; b2 = n2; b3 = n3;
  }
#undef LDB
#pragma unroll
  for (int r = 0; r < 4; ++r)
    for (int off = 1; off < 16; off <<= 1) s[r] += __shfl_xor(s[r], off, 64);
  if (i16 == 0) {
#pragma unroll
    for (int r = 0; r < 4; ++r) atomicAdd(&sums[nbase + q * 4 + r], s[r]);
  }
}

// ---- yT[col][n] = bf16(x[bc][n][t] / sums[n]) via LDS transpose (pad 12->13) ----
__global__ __launch_bounds__(256) void k_y(const float* __restrict__ x,
                                           const float* __restrict__ sums,
                                           unsigned short* __restrict__ yT) {
  __shared__ float xs[3328];  // 256 * 13
  const int tid = threadIdx.x;
  const int n0 = blockIdx.x * 256;
  const int bc = blockIdx.y;
  const float* xp = x + (size_t)bc * NN * TT + (size_t)n0 * TT;
#pragma unroll
  for (int j = 0; j < 12; ++j) {
    const int idx = j * 256 + tid;
    xs[(idx / 12) * 13 + idx % 12] = xp[idx];
  }
  __syncthreads();
  const float rinv = 1.0f / sums[n0 + tid];
#pragma unroll
  for (int t = 0; t < 12; ++t)
    yT[(size_t)(bc * TT + t) * NN + n0 + tid] = f2bf(xs[tid * 13 + t] * rinv);
}

// ---- k_mega: part[nc][col][m] = sum_{n in chunk} E[n][m] * y[col][n] ----
// grid (128 m-blocks of 64, 8 chunks of 1024 n); 256 thr = 4 waves.
// Stage = 64 n, double-buffered Et[2][64][ESTR]. Gen: wave w -> E rows
// [w*16,w*16+16) x 64 n (4 MFMAs + 16 exp2 + 4 b64 writes). Acc: wave w ->
// coltiles [w*3,w*3+3) x 4 m-subs x 2 k-steps = 24 MFMAs. One RAW barrier
// per stage. All 6 y loads issued at stage top (half-1 latency hides
// under k-step-0 MFMAs). 4 blocks/CU = 4 independent barrier domains.
__global__ __launch_bounds__(256, 4) void k_mega(const unsigned short* __restrict__ t1b,
                                                 const unsigned short* __restrict__ nv2b,
                                                 const unsigned short* __restrict__ yT,
                                                 float* __restrict__ part) {
  const int tid = threadIdx.x;
  const int w = tid >> 6, lane = tid & 63, q = lane >> 4, i16 = lane & 15;
  const int mb = blockIdx.x * 64;
  const int nt0 = blockIdx.y * CHUNK;

  __shared__ unsigned short Ew[2][64][ESTR];  // 17920 B

  // gen B-frag (loop-invariant): B[d][m=i16] = nv2[mb + w*16 + i16][d]
  const bf16x8 bg = *(const bf16x8*)(nv2b + (size_t)(mb + w * 16 + i16) * DD + q * 8);
  const int rowm = w * 16 + i16;

  const f32x4 z4 = {0.f, 0.f, 0.f, 0.f};
  f32x4 acc[3][4];
#pragma unroll
  for (int c = 0; c < 3; ++c)
#pragma unroll
    for (int ms = 0; ms < 4; ++ms) acc[c][ms] = (f32x4){0.f, 0.f, 0.f, 0.f};

  // ---- prologue: generate stage 0 (64 n) into buf 0 ----
#pragma unroll
  for (int s = 0; s < 4; ++s) {
    bf16x8 at = *(const bf16x8*)(t1b + (size_t)(nt0 + s * 16 + i16) * DD + q * 8);
    f32x4 d = __builtin_amdgcn_mfma_f32_16x16x32_bf16(at, bg, z4, 0, 0, 0);
    bf16x4 e;
#pragma unroll
    for (int r = 0; r < 4; ++r) e[r] = (short)f2bf(fexp2(fmaxf(d[r], 0.f)));
    *(bf16x4*)&Ew[0][rowm][s * 16 + q * 4] = e;
  }
  RAWBAR();

  int p = 0;
  for (int st = 0; st < 16; ++st, p ^= 1) {
    const int nt = nt0 + st * 64;
    const bool more = (st < 15);

    // --- stage top: issue ALL global loads (y both halves, next t1) ---
    bf16x8 yfr0[3], yfr1[3];
#pragma unroll
    for (int c = 0; c < 3; ++c) {
      const unsigned short* ybase = yT + (size_t)((w * 3 + c) * 16 + i16) * NN + nt + q * 8;
      yfr0[c] = *(const bf16x8*)ybase;
      yfr1[c] = *(const bf16x8*)(ybase + 32);
    }
    bf16x8 atn[4];
    if (more) {
#pragma unroll
      for (int s = 0; s < 4; ++s)
        atn[s] = *(const bf16x8*)(t1b + (size_t)(nt + 64 + s * 16 + i16) * DD + q * 8);
    }

    // half-0 E operands
    bf16x8 efr[4];
#pragma unroll
    for (int ms = 0; ms < 4; ++ms)
      efr[ms] = *(const bf16x8*)&Ew[p][ms * 16 + i16][q * 8];

    // gen first half (s0,s1) for stage st+1
    f32x4 d0, d1;
    if (more) {
      d0 = __builtin_amdgcn_mfma_f32_16x16x32_bf16(atn[0], bg, z4, 0, 0, 0);
      d1 = __builtin_amdgcn_mfma_f32_16x16x32_bf16(atn[1], bg, z4, 0, 0, 0);
    }

    // acc k-step 0 (12 MFMAs)
#pragma unroll
    for (int c = 0; c < 3; ++c)
#pragma unroll
      for (int ms = 0; ms < 4; ++ms)
        acc[c][ms] = __builtin_amdgcn_mfma_f32_16x16x32_bf16(yfr0[c], efr[ms], acc[c][ms], 0, 0, 0);

    // exp2 + store s0,s1; gen + store s2,s3 (VALU overlaps MFMA pipes)
    if (more) {
      bf16x4 e0, e1;
#pragma unroll
      for (int r = 0; r < 4; ++r) {
        e0[r] = (short)f2bf(fexp2(fmaxf(d0[r], 0.f)));
        e1[r] = (short)f2bf(fexp2(fmaxf(d1[r], 0.f)));
      }
      *(bf16x4*)&Ew[p ^ 1][rowm][q * 4] = e0;
      *(bf16x4*)&Ew[p ^ 1][rowm][16 + q * 4] = e1;
      f32x4 d2 = __builtin_amdgcn_mfma_f32_16x16x32_bf16(atn[2], bg, z4, 0, 0, 0);
      f32x4 d3 = __builtin_amdgcn_mfma_f32_16x16x32_bf16(atn[3], bg, z4, 0, 0, 0);
      bf16x4 e2, e3;
#pragma unroll
      for (int r = 0; r < 4; ++r) {
        e2[r] = (short)f2bf(fexp2(fmaxf(d2[r], 0.f)));
        e3[r] = (short)f2bf(fexp2(fmaxf(d3[r], 0.f)));
      }
      *(bf16x4*)&Ew[p ^ 1][rowm][32 + q * 4] = e2;
      *(bf16x4*)&Ew[p ^ 1][rowm][48 + q * 4] = e3;
    }

    // half-1 E operands + acc (k-step 1: n 32..63)
#pragma unroll
    for (int ms = 0; ms < 4; ++ms)
      efr[ms] = *(const bf16x8*)&Ew[p][ms * 16 + i16][32 + q * 8];
#pragma unroll
    for (int c = 0; c < 3; ++c)
#pragma unroll
      for (int ms = 0; ms < 4; ++ms)
        acc[c][ms] = __builtin_amdgcn_mfma_f32_16x16x32_bf16(yfr1[c], efr[ms], acc[c][ms], 0, 0, 0);

    RAWBAR();  // buf p reads done; buf p^1 writes visible (lgkmcnt only)
  }

  // epilogue: lane holds col = (w*3+c)*16 + q*4 + r, m = mb + ms*16 + i16
  float* pp = part + (size_t)blockIdx.y * 192 * NN;
#pragma unroll
  for (int c = 0; c < 3; ++c)
#pragma unroll
    for (int ms = 0; ms < 4; ++ms) {
      const int colbase = (w * 3 + c) * 16 + q * 4;
      const int m = mb + ms * 16 + i16;
#pragma unroll
      for (int r = 0; r < 4; ++r)
        pp[(size_t)(colbase + r) * NN + m] = acc[c][ms][r];
    }
}

// ---- reduce NSPLIT partials + transpose to out[bc][m][t] (pad 12->13) ----
__global__ __launch_bounds__(256) void k_reduce(const float* __restrict__ part,
                                                float* __restrict__ out) {
  __shared__ float os[3328];  // 256 * 13
  const int tid = threadIdx.x;
  const int m0 = blockIdx.x * 256;
  const int bc = blockIdx.y;
#pragma unroll
  for (int t = 0; t < 12; ++t) {
    const int col = bc * TT + t;
    float s = 0.f;
#pragma unroll
    for (int nc = 0; nc < NSPLIT; ++nc)
      s += part[((size_t)nc * 192 + col) * NN + m0 + tid];
    os[tid * 13 + t] = s;
  }
  __syncthreads();
  float* op = out + (size_t)bc * NN * TT + (size_t)m0 * TT;
#pragma unroll
  for (int j = 0; j < 12; ++j) {
    const int idx = j * 256 + tid;
    op[idx] = os[(idx / 12) * 13 + idx % 12];
  }
}

extern "C" void kernel_launch(void* const* d_in, const int* in_sizes, int n_in,
                              void* d_out, int out_size, void* d_ws, size_t ws_size,
                              hipStream_t stream) {
  const float* x = (const float*)d_in[0];
  const float* nv1 = (const float*)d_in[1];
  const float* nv2 = (const float*)d_in[2];
  const float* tv = (const float*)d_in[3];
  const float* kk = (const float*)d_in[4];
  const int* tind = (const int*)d_in[5];
  float* out = (float*)d_out;

  char* ws = (char*)d_ws;
  unsigned short* t1b  = (unsigned short*)(ws);            //  524288 B
  unsigned short* nv2b = (unsigned short*)(ws + 524288);   //  524288 B
  float* sums          = (float*)(ws + 1048576);           //   32768 B
  unsigned short* yT   = (unsigned short*)(ws + 1081344);  // 3145728 B -> 4227072
  float* part          = (float*)(ws + 4227072);           // 50331648 B -> 54558720

  k_prep<<<128, 256, 0, stream>>>(nv1, nv2, tv, kk, tind, t1b, nv2b, sums);
  k_stats<<<dim3(128, 8), 256, 0, stream>>>(t1b, nv2b, sums);
  k_y<<<dim3(32, 16), 256, 0, stream>>>(x, sums, yT);
  k_mega<<<dim3(128, NSPLIT), 256, 0, stream>>>(t1b, nv2b, yT, part);
  k_reduce<<<dim3(32, 16), 256, 0, stream>>>(part, out);
}

// Round 10
// 172.189 us; speedup vs baseline: 1.2679x; 1.0046x over previous
//
#include <hip/hip_runtime.h>
#include <hip/hip_bf16.h>

// GDGCN: out[b,c,m,t] = sum_n softmax_row(relu(t1 nv2^T))[n,m] * x[b,c,n,t]
// t1 = nv1 @ (sum_d tv[d] k[d,:,:]);  N=8192, D=32, cols = B*C*T = 192.
// R21 == R20 resubmitted verbatim (R20's bench was an infra failure:
// "MI355X container failed twice" -- no signal). Changes vs R19:
//  1) part buffer f32 -> bf16: k_mega HBM write 49->24.6MB, k_reduce HBM
//     read 50->25MB (part exceeds L2; this is real HBM traffic, ~8us).
//     Error budget: +2e-3 abs on 0.0156, threshold 0.0269.
//  2) k_stats m-split 8->16 (512-m chunks, 2048 blocks = 8 blocks/CU =
//     8 waves/SIMD at ~28 VGPR): 2x TLP for its L2-bound b-loads.
//  3) k_mega: s_setprio(1/0) around each 12-MFMA acc cluster (T5).
// k_mega learnings: bank conflicts NOT critical (3.1M vs 5.2M, zero dt);
// barrier drain NOT critical (RAWBAR neutral); y issue distance NOT
// critical (hoist neutral). m-split redesigns all lost (R15/16/17).
// E-pack: bit-exact RNE f2bf only (v_cvt_pk_bf16_f32 NOT RNE, R14).

#define NN 8192
#define DD 32
#define TT 12
#define NSPLIT 8
#define CHUNK 1024
#define ESTR 70  // LDS row stride (ushort)

typedef __attribute__((ext_vector_type(8))) short bf16x8;
typedef __attribute__((ext_vector_type(4))) short bf16x4;
typedef __attribute__((ext_vector_type(4))) float f32x4;

static __device__ __forceinline__ unsigned short f2bf(float f) {
  unsigned int u = __float_as_uint(f);
  u = (u + 0x7FFFu + ((u >> 16) & 1u)) >> 16;  // RNE bf16
  return (unsigned short)u;
}

static __device__ __forceinline__ float fexp2(float x) {
#if __has_builtin(__builtin_amdgcn_exp2f)
  return __builtin_amdgcn_exp2f(x);
#else
  return __builtin_exp2f(x);
#endif
}

// Raw barrier: LDS-visibility only (lgkmcnt). Global loads stay in flight.
#define RAWBAR()                                          \
  do {                                                    \
    asm volatile("s_waitcnt lgkmcnt(0)" ::: "memory");    \
    __builtin_amdgcn_sched_barrier(0);                    \
    __builtin_amdgcn_s_barrier();                         \
  } while (0)

// ---- fused: core = tv.k ; t1 = (nv1@core)*log2e (bf16) ; nv2 -> bf16 ; sums=0
// 128 blocks x 64 rows.
__global__ __launch_bounds__(256) void k_prep(const float* __restrict__ nv1,
                                              const float* __restrict__ nv2,
                                              const float* __restrict__ timevec,
                                              const float* __restrict__ kk,
                                              const int* __restrict__ tind,
                                              unsigned short* __restrict__ t1b,
                                              unsigned short* __restrict__ nv2b,
                                              float* __restrict__ sums) {
  __shared__ float cs[1024];
  const int tid = threadIdx.x;
  if (tid < 64) sums[blockIdx.x * 64 + tid] = 0.f;
  const float* tv = timevec + (size_t)tind[0] * DD;
  for (int idx = tid; idx < 1024; idx += 256) {
    float acc = 0.f;
#pragma unroll
    for (int d = 0; d < DD; ++d) acc += tv[d] * kk[d * 1024 + idx];
    cs[idx] = acc;
  }
  __syncthreads();
  const int nbase = blockIdx.x * 64;
  const int f = tid & 31, sub = tid >> 5;
#pragma unroll 4
  for (int it = 0; it < 8; ++it) {
    const int n = nbase + it * 8 + sub;
    const float* nr = nv1 + (size_t)n * DD;
    float acc = 0.f;
#pragma unroll
    for (int e = 0; e < DD; ++e) acc += nr[e] * cs[e * DD + f];
    t1b[(size_t)n * DD + f] = f2bf(acc * 1.4426950408889634f);  // fold log2(e)
  }
#pragma unroll 4
  for (int it = 0; it < 8; ++it) {
    const int idx = nbase * DD + it * 256 + tid;
    nv2b[idx] = f2bf(nv2[idx]);
  }
}

// ---- sums[n] += sum_m exp2(relu(t1[n].nv2[m]))  grid (128 n, 16 m-chunks) ----
// 512-m chunks -> 2048 blocks = 8 blocks/CU for latency hiding.
// 1-iter b-prefetch: loads of tile mt+64 issued before computing tile mt.
__global__ __launch_bounds__(256) void k_stats(const unsigned short* __restrict__ t1b,
                                               const unsigned short* __restrict__ nv2b,
                                               float* __restrict__ sums) {
  const int tid = threadIdx.x;
  const int w = tid >> 6, lane = tid & 63, q = lane >> 4, i16 = lane & 15;
  const int nbase = blockIdx.x * 64 + w * 16;
  bf16x8 a = *(const bf16x8*)(t1b + (size_t)(nbase + i16) * DD + q * 8);
  const f32x4 z4 = {0.f, 0.f, 0.f, 0.f};
  float s[4] = {0.f, 0.f, 0.f, 0.f};
  const int m0 = blockIdx.y * 512;
#define LDB(mt, u) (*(const bf16x8*)(nv2b + (size_t)((mt) + (u)*16 + i16) * DD + q * 8))
  bf16x8 b0 = LDB(m0, 0), b1 = LDB(m0, 1), b2 = LDB(m0, 2), b3 = LDB(m0, 3);
  for (int mt = m0; mt < m0 + 512; mt += 64) {
    const int mtn = (mt + 64 < m0 + 512) ? (mt + 64) : mt;  // clamp: dummy reload
    bf16x8 n0 = LDB(mtn, 0), n1 = LDB(mtn, 1), n2 = LDB(mtn, 2), n3 = LDB(mtn, 3);
    f32x4 d;
    d = __builtin_amdgcn_mfma_f32_16x16x32_bf16(a, b0, z4, 0, 0, 0);
#pragma unroll
    for (int r = 0; r < 4; ++r) s[r] += fexp2(fmaxf(d[r], 0.f));
    d = __builtin_amdgcn_mfma_f32_16x16x32_bf16(a, b1, z4, 0, 0, 0);
#pragma unroll
    for (int r = 0; r < 4; ++r) s[r] += fexp2(fmaxf(d[r], 0.f));
    d = __builtin_amdgcn_mfma_f32_16x16x32_bf16(a, b2, z4, 0, 0, 0);
#pragma unroll
    for (int r = 0; r < 4; ++r) s[r] += fexp2(fmaxf(d[r], 0.f));
    d = __builtin_amdgcn_mfma_f32_16x16x32_bf16(a, b3, z4, 0, 0, 0);
#pragma unroll
    for (int r = 0; r < 4; ++r) s[r] += fexp2(fmaxf(d[r], 0.f));
    b0 = n0; b1 = n1; b2 = n2; b3 = n3;
  }
#undef LDB
#pragma unroll
  for (int r = 0; r < 4; ++r)
    for (int off = 1; off < 16; off <<= 1) s[r] += __shfl_xor(s[r], off, 64);
  if (i16 == 0) {
#pragma unroll
    for (int r = 0; r < 4; ++r) atomicAdd(&sums[nbase + q * 4 + r], s[r]);
  }
}

// ---- yT[col][n] = bf16(x[bc][n][t] / sums[n]) via LDS transpose (pad 12->13) ----
__global__ __launch_bounds__(256) void k_y(const float* __restrict__ x,
                                           const float* __restrict__ sums,
                                           unsigned short* __restrict__ yT) {
  __shared__ float xs[3328];  // 256 * 13
  const int tid = threadIdx.x;
  const int n0 = blockIdx.x * 256;
  const int bc = blockIdx.y;
  const float* xp = x + (size_t)bc * NN * TT + (size_t)n0 * TT;
#pragma unroll
  for (int j = 0; j < 12; ++j) {
    const int idx = j * 256 + tid;
    xs[(idx / 12) * 13 + idx % 12] = xp[idx];
  }
  __syncthreads();
  const float rinv = 1.0f / sums[n0 + tid];
#pragma unroll
  for (int t = 0; t < 12; ++t)
    yT[(size_t)(bc * TT + t) * NN + n0 + tid] = f2bf(xs[tid * 13 + t] * rinv);
}

// ---- k_mega: part[nc][col][m] = sum_{n in chunk} E[n][m] * y[col][n] ----
// grid (128 m-blocks of 64, 8 chunks of 1024 n); 256 thr = 4 waves.
// Stage = 64 n, double-buffered Et[2][64][ESTR]. Gen: wave w -> E rows
// [w*16,+16) x 64 n. Acc: wave w -> coltiles [w*3,+3) x 4 m-subs x 2
// k-steps = 24 MFMAs, setprio-wrapped. One RAW barrier per stage.
// part output in bf16 (halves HBM write).
__global__ __launch_bounds__(256, 4) void k_mega(const unsigned short* __restrict__ t1b,
                                                 const unsigned short* __restrict__ nv2b,
                                                 const unsigned short* __restrict__ yT,
                                                 unsigned short* __restrict__ part) {
  const int tid = threadIdx.x;
  const int w = tid >> 6, lane = tid & 63, q = lane >> 4, i16 = lane & 15;
  const int mb = blockIdx.x * 64;
  const int nt0 = blockIdx.y * CHUNK;

  __shared__ unsigned short Ew[2][64][ESTR];  // 17920 B

  // gen B-frag (loop-invariant): B[d][m=i16] = nv2[mb + w*16 + i16][d]
  const bf16x8 bg = *(const bf16x8*)(nv2b + (size_t)(mb + w * 16 + i16) * DD + q * 8);
  const int rowm = w * 16 + i16;

  const f32x4 z4 = {0.f, 0.f, 0.f, 0.f};
  f32x4 acc[3][4];
#pragma unroll
  for (int c = 0; c < 3; ++c)
#pragma unroll
    for (int ms = 0; ms < 4; ++ms) acc[c][ms] = (f32x4){0.f, 0.f, 0.f, 0.f};

  // ---- prologue: generate stage 0 (64 n) into buf 0 ----
#pragma unroll
  for (int s = 0; s < 4; ++s) {
    bf16x8 at = *(const bf16x8*)(t1b + (size_t)(nt0 + s * 16 + i16) * DD + q * 8);
    f32x4 d = __builtin_amdgcn_mfma_f32_16x16x32_bf16(at, bg, z4, 0, 0, 0);
    bf16x4 e;
#pragma unroll
    for (int r = 0; r < 4; ++r) e[r] = (short)f2bf(fexp2(fmaxf(d[r], 0.f)));
    *(bf16x4*)&Ew[0][rowm][s * 16 + q * 4] = e;
  }
  RAWBAR();

  int p = 0;
  for (int st = 0; st < 16; ++st, p ^= 1) {
    const int nt = nt0 + st * 64;
    const bool more = (st < 15);

    // --- stage top: issue ALL global loads (y both halves, next t1) ---
    bf16x8 yfr0[3], yfr1[3];
#pragma unroll
    for (int c = 0; c < 3; ++c) {
      const unsigned short* ybase = yT + (size_t)((w * 3 + c) * 16 + i16) * NN + nt + q * 8;
      yfr0[c] = *(const bf16x8*)ybase;
      yfr1[c] = *(const bf16x8*)(ybase + 32);
    }
    bf16x8 atn[4];
    if (more) {
#pragma unroll
      for (int s = 0; s < 4; ++s)
        atn[s] = *(const bf16x8*)(t1b + (size_t)(nt + 64 + s * 16 + i16) * DD + q * 8);
    }

    // half-0 E operands
    bf16x8 efr[4];
#pragma unroll
    for (int ms = 0; ms < 4; ++ms)
      efr[ms] = *(const bf16x8*)&Ew[p][ms * 16 + i16][q * 8];

    // gen first half (s0,s1) for stage st+1
    f32x4 d0, d1;
    if (more) {
      d0 = __builtin_amdgcn_mfma_f32_16x16x32_bf16(atn[0], bg, z4, 0, 0, 0);
      d1 = __builtin_amdgcn_mfma_f32_16x16x32_bf16(atn[1], bg, z4, 0, 0, 0);
    }

    // acc k-step 0 (12 MFMAs), priority-boosted (T5)
    __builtin_amdgcn_s_setprio(1);
#pragma unroll
    for (int c = 0; c < 3; ++c)
#pragma unroll
      for (int ms = 0; ms < 4; ++ms)
        acc[c][ms] = __builtin_amdgcn_mfma_f32_16x16x32_bf16(yfr0[c], efr[ms], acc[c][ms], 0, 0, 0);
    __builtin_amdgcn_s_setprio(0);

    // exp2 + store s0,s1; gen + store s2,s3 (VALU overlaps MFMA pipes)
    if (more) {
      bf16x4 e0, e1;
#pragma unroll
      for (int r = 0; r < 4; ++r) {
        e0[r] = (short)f2bf(fexp2(fmaxf(d0[r], 0.f)));
        e1[r] = (short)f2bf(fexp2(fmaxf(d1[r], 0.f)));
      }
      *(bf16x4*)&Ew[p ^ 1][rowm][q * 4] = e0;
      *(bf16x4*)&Ew[p ^ 1][rowm][16 + q * 4] = e1;
      f32x4 d2 = __builtin_amdgcn_mfma_f32_16x16x32_bf16(atn[2], bg, z4, 0, 0, 0);
      f32x4 d3 = __builtin_amdgcn_mfma_f32_16x16x32_bf16(atn[3], bg, z4, 0, 0, 0);
      bf16x4 e2, e3;
#pragma unroll
      for (int r = 0; r < 4; ++r) {
        e2[r] = (short)f2bf(fexp2(fmaxf(d2[r], 0.f)));
        e3[r] = (short)f2bf(fexp2(fmaxf(d3[r], 0.f)));
      }
      *(bf16x4*)&Ew[p ^ 1][rowm][32 + q * 4] = e2;
      *(bf16x4*)&Ew[p ^ 1][rowm][48 + q * 4] = e3;
    }

    // half-1 E operands + acc (k-step 1: n 32..63)
#pragma unroll
    for (int ms = 0; ms < 4; ++ms)
      efr[ms] = *(const bf16x8*)&Ew[p][ms * 16 + i16][32 + q * 8];
    __builtin_amdgcn_s_setprio(1);
#pragma unroll
    for (int c = 0; c < 3; ++c)
#pragma unroll
      for (int ms = 0; ms < 4; ++ms)
        acc[c][ms] = __builtin_amdgcn_mfma_f32_16x16x32_bf16(yfr1[c], efr[ms], acc[c][ms], 0, 0, 0);
    __builtin_amdgcn_s_setprio(0);

    RAWBAR();  // buf p reads done; buf p^1 writes visible (lgkmcnt only)
  }

  // epilogue: lane holds col = (w*3+c)*16 + q*4 + r, m = mb + ms*16 + i16
  unsigned short* pp = part + (size_t)blockIdx.y * 192 * NN;
#pragma unroll
  for (int c = 0; c < 3; ++c)
#pragma unroll
    for (int ms = 0; ms < 4; ++ms) {
      const int colbase = (w * 3 + c) * 16 + q * 4;
      const int m = mb + ms * 16 + i16;
#pragma unroll
      for (int r = 0; r < 4; ++r)
        pp[(size_t)(colbase + r) * NN + m] = f2bf(acc[c][ms][r]);
    }
}

// ---- reduce NSPLIT bf16 partials + transpose to out[bc][m][t] (pad 12->13) ----
__global__ __launch_bounds__(256) void k_reduce(const unsigned short* __restrict__ part,
                                                float* __restrict__ out) {
  __shared__ float os[3328];  // 256 * 13
  const int tid = threadIdx.x;
  const int m0 = blockIdx.x * 256;
  const int bc = blockIdx.y;
#pragma unroll
  for (int t = 0; t < 12; ++t) {
    const int col = bc * TT + t;
    float s = 0.f;
#pragma unroll
    for (int nc = 0; nc < NSPLIT; ++nc) {
      const unsigned int u = part[((size_t)nc * 192 + col) * NN + m0 + tid];
      s += __uint_as_float(u << 16);
    }
    os[tid * 13 + t] = s;
  }
  __syncthreads();
  float* op = out + (size_t)bc * NN * TT + (size_t)m0 * TT;
#pragma unroll
  for (int j = 0; j < 12; ++j) {
    const int idx = j * 256 + tid;
    op[idx] = os[(idx / 12) * 13 + idx % 12];
  }
}

extern "C" void kernel_launch(void* const* d_in, const int* in_sizes, int n_in,
                              void* d_out, int out_size, void* d_ws, size_t ws_size,
                              hipStream_t stream) {
  const float* x = (const float*)d_in[0];
  const float* nv1 = (const float*)d_in[1];
  const float* nv2 = (const float*)d_in[2];
  const float* tv = (const float*)d_in[3];
  const float* kk = (const float*)d_in[4];
  const int* tind = (const int*)d_in[5];
  float* out = (float*)d_out;

  char* ws = (char*)d_ws;
  unsigned short* t1b  = (unsigned short*)(ws);            //  524288 B
  unsigned short* nv2b = (unsigned short*)(ws + 524288);   //  524288 B
  float* sums          = (float*)(ws + 1048576);           //   32768 B
  unsigned short* yT   = (unsigned short*)(ws + 1081344);  // 3145728 B -> 4227072
  unsigned short* part = (unsigned short*)(ws + 4227072);  // 25165824 B (bf16) -> 29392896

  k_prep<<<128, 256, 0, stream>>>(nv1, nv2, tv, kk, tind, t1b, nv2b, sums);
  k_stats<<<dim3(128, 16), 256, 0, stream>>>(t1b, nv2b, sums);
  k_y<<<dim3(32, 16), 256, 0, stream>>>(x, sums, yT);
  k_mega<<<dim3(128, NSPLIT), 256, 0, stream>>>(t1b, nv2b, yT, part);
  k_reduce<<<dim3(32, 16), 256, 0, stream>>>(part, out);
}